// Round 1
// baseline (490.747 us; speedup 1.0000x reference)
//
#include <hip/hip_runtime.h>

#define B_   512
#define N_   512
#define FIN_ 2
#define F_   128
#define G_   512   // 4*F gates

typedef _Float16 half8 __attribute__((ext_vector_type(8)));
typedef float    float4_ __attribute__((ext_vector_type(4)));

__device__ __forceinline__ float sigmoid_(float x) {
    return __builtin_amdgcn_rcpf(1.f + __expf(-x));
}
__device__ __forceinline__ float tanh_(float x) {
    // tanh(x) = 1 - 2/(exp(2x)+1); saturates correctly at +-inf
    return 1.f - 2.f * __builtin_amdgcn_rcpf(1.f + __expf(2.f * x));
}

// One workgroup = one batch row. 4 waves; wave w owns hidden dims
// j in [w*32, w*32+32) i.e. gate columns {i,f,g,o} x those j (permuted tiles).
// Weights persist in registers as MFMA B-fragments for all 512 steps.
__global__ void __launch_bounds__(256, 2)
lstm_scan(const float* __restrict__ inp, const float* __restrict__ Wk,
          const float* __restrict__ bias, float* __restrict__ out)
{
    const int bb   = blockIdx.x;       // batch element
    const int tid  = threadIdx.x;
    const int w    = tid >> 6;         // wave 0..3
    const int lane = tid & 63;
    const int c15  = lane & 15;        // col within 16-col tile / A row idx
    const int grp  = lane >> 4;        // k-group (8 consecutive k)
    const int jj   = lane & 31;        // hidden dim within wave's 32 (lanes<32)

    __shared__ __align__(16) _Float16 h_lds[2][F_];   // ping-pong hidden state
    __shared__ float gate_lds[4][128];                // per-wave private gates

    // ---- one-time: load weight fragments into registers ----
    // tile t (0..7): gate g = t>>1, cols jj = (t&1)*16 + c15 (of wave's 32)
    half8 wf[8][4];
    float w0r[8], w1r[8], br[8];
#pragma unroll
    for (int t = 0; t < 8; ++t) {
        const int col = (t >> 1) * 128 + w * 32 + (t & 1) * 16 + c15;
        w0r[t] = Wk[0 * G_ + col];
        w1r[t] = Wk[1 * G_ + col];
        br[t]  = bias[col];
#pragma unroll
        for (int s2 = 0; s2 < 4; ++s2) {
            half8 f;
#pragma unroll
            for (int e = 0; e < 8; ++e) {
                const int k = s2 * 32 + grp * 8 + e;   // 0..127
                f[e] = (_Float16)Wk[(size_t)(2 + k) * G_ + col];
            }
            wf[t][s2] = f;
        }
    }

    if (tid < F_) {
        h_lds[0][tid] = (_Float16)0.f;
        h_lds[1][tid] = (_Float16)0.f;
    }
    __syncthreads();

    float c_state = 0.f;   // valid for lanes < 32
    int p = 0;

    for (int s = 0; s < N_; ++s) {
        // x_shift: zeros at s==0, else inputs[bb, s-1, :]  (uniform scalars)
        float x0 = 0.f, x1 = 0.f;
        if (s > 0) {
            const float* xr = inp + ((size_t)bb * N_ + (s - 1)) * FIN_;
            x0 = xr[0];
            x1 = xr[1];
        }

        // A-fragments: only row 0 (c15==0 lanes) carries h; rest zero
        half8 af[4];
#pragma unroll
        for (int s2 = 0; s2 < 4; ++s2) {
            half8 v;
#pragma unroll
            for (int e = 0; e < 8; ++e) v[e] = (_Float16)0.f;
            if (c15 == 0)
                v = *reinterpret_cast<const half8*>(&h_lds[p][s2 * 32 + grp * 8]);
            af[s2] = v;
        }

        // C-init = x-projection + bias (fp32 exact), row 0 only
        float4_ acc[8];
#pragma unroll
        for (int t = 0; t < 8; ++t) {
            const float xpv = fmaf(x0, w0r[t], fmaf(x1, w1r[t], br[t]));
            acc[t][0] = (lane < 16) ? xpv : 0.f;
            acc[t][1] = 0.f; acc[t][2] = 0.f; acc[t][3] = 0.f;
        }

        // h @ Wh : 8 col-tiles x 4 K-slices
#pragma unroll
        for (int s2 = 0; s2 < 4; ++s2)
#pragma unroll
            for (int t = 0; t < 8; ++t)
                acc[t] = __builtin_amdgcn_mfma_f32_16x16x32_f16(af[s2], wf[t][s2], acc[t], 0, 0, 0);

        // gates row 0: lanes 0..15, reg 0 of each tile -> wave-local LDS
        if (lane < 16) {
#pragma unroll
            for (int t = 0; t < 8; ++t)
                gate_lds[w][t * 16 + c15] = acc[t][0];   // == [gate g][jj] layout
        }
        __syncthreads();

        if (lane < 32) {
            const float gi = gate_lds[w][0 * 32 + jj];
            const float gf = gate_lds[w][1 * 32 + jj];
            const float gg = gate_lds[w][2 * 32 + jj];
            const float go = gate_lds[w][3 * 32 + jj];
            const float si = sigmoid_(gi);
            const float sf = sigmoid_(gf);
            const float so = sigmoid_(go);
            const float tg = tanh_(gg);
            c_state = fmaf(sf, c_state, si * tg);
            const float hv = so * tanh_(c_state);
            out[((size_t)bb * N_ + s) * F_ + w * 32 + jj] = hv;
            h_lds[p ^ 1][w * 32 + jj] = (_Float16)hv;
        }
        __syncthreads();
        p ^= 1;
    }
}

extern "C" void kernel_launch(void* const* d_in, const int* in_sizes, int n_in,
                              void* d_out, int out_size, void* d_ws, size_t ws_size,
                              hipStream_t stream) {
    const float* inp  = (const float*)d_in[0];
    const float* Wk   = (const float*)d_in[1];
    const float* bias = (const float*)d_in[2];
    float* out        = (float*)d_out;
    lstm_scan<<<dim3(B_), dim3(256), 0, stream>>>(inp, Wk, bias, out);
}

// Round 2
// 401.896 us; speedup vs baseline: 1.2211x; 1.2211x over previous
//
#include <hip/hip_runtime.h>

#define B_   512
#define N_   512
#define FIN_ 2
#define F_   128
#define G_   512   // 4*F gates

typedef _Float16 half8 __attribute__((ext_vector_type(8)));
typedef float    float4_ __attribute__((ext_vector_type(4)));

__device__ __forceinline__ float sigmoid_(float x) {
    return __builtin_amdgcn_rcpf(1.f + __expf(-x));
}
__device__ __forceinline__ float tanh_(float x) {
    // tanh(x) = 1 - 2/(exp(2x)+1); saturates correctly at +-inf
    return 1.f - 2.f * __builtin_amdgcn_rcpf(1.f + __expf(2.f * x));
}

// One LSTM step. hsrc/hdst are the ping-pong LDS hidden buffers (static).
// Lanes 0..15 own 2 hidden dims each (cols c15 and c15+16 of the wave's 32):
// tile t -> gate t>>1, col half t&1 — so row 0 of the 8 tiles hands each lane
// all 4 gates for its 2 dims with NO cross-lane redistribution.
__device__ __forceinline__ void lstm_step(
    const _Float16* __restrict__ hsrc, _Float16* __restrict__ hdst,
    const half8 (&wf)[8][4], const float (&w0r)[8], const float (&w1r)[8],
    const float (&br)[8], float4_ (&acc)[8], float x0, float x1,
    float& cs0, float& cs1, float* outp, int lane, int c15, int grp, int w)
{
    // A-fragments: broadcast h into ALL 16 A-rows (rows 1..15 of C are never
    // read, so no zero-fill / no per-lane branch needed).
    half8 af[4];
#pragma unroll
    for (int s2 = 0; s2 < 4; ++s2)
        af[s2] = *reinterpret_cast<const half8*>(&hsrc[s2 * 32 + grp * 8]);

    // C-init row 0 = x-projection + bias (fp32 exact). Regs 1..3 stay stale.
#pragma unroll
    for (int t = 0; t < 8; ++t)
        acc[t][0] = fmaf(x0, w0r[t], fmaf(x1, w1r[t], br[t]));

    // h @ Wh : 8 col-tiles x 4 K-slices (K=128)
#pragma unroll
    for (int s2 = 0; s2 < 4; ++s2)
#pragma unroll
        for (int t = 0; t < 8; ++t)
            acc[t] = __builtin_amdgcn_mfma_f32_16x16x32_f16(af[s2], wf[t][s2], acc[t], 0, 0, 0);

    if (lane < 16) {
        const float i0 = sigmoid_(acc[0][0]), i1 = sigmoid_(acc[1][0]);
        const float f0 = sigmoid_(acc[2][0]), f1 = sigmoid_(acc[3][0]);
        const float g0 = tanh_(acc[4][0]),    g1 = tanh_(acc[5][0]);
        const float o0 = sigmoid_(acc[6][0]), o1 = sigmoid_(acc[7][0]);
        cs0 = fmaf(f0, cs0, i0 * g0);
        cs1 = fmaf(f1, cs1, i1 * g1);
        const float h0 = o0 * tanh_(cs0);
        const float h1 = o1 * tanh_(cs1);
        outp[0]  = h0;          // fire-and-forget; never drained by a barrier
        outp[16] = h1;
        hdst[w * 32 + c15]      = (_Float16)h0;
        hdst[w * 32 + c15 + 16] = (_Float16)h1;
    }
    // LDS-visibility-only barrier: do NOT drain vmcnt (out stores in flight).
    asm volatile("s_waitcnt lgkmcnt(0)\n\ts_barrier" ::: "memory");
}

__global__ void __launch_bounds__(256, 2)
lstm_scan(const float* __restrict__ inp, const float* __restrict__ Wk,
          const float* __restrict__ bias, float* __restrict__ out)
{
    const int bb   = blockIdx.x;       // batch element
    const int tid  = threadIdx.x;
    const int w    = tid >> 6;         // wave 0..3
    const int lane = tid & 63;
    const int c15  = lane & 15;        // col within 16-col tile
    const int grp  = lane >> 4;        // k-group (8 consecutive k)

    __shared__ __align__(16) _Float16 h_lds[2][F_];   // ping-pong hidden state

    // ---- one-time: load weight fragments into registers ----
    // tile t (0..7): gate g = t>>1, cols = (t&1)*16 + c15 (of wave's 32)
    half8 wf[8][4];
    float w0r[8], w1r[8], br[8];
#pragma unroll
    for (int t = 0; t < 8; ++t) {
        const int col = (t >> 1) * 128 + w * 32 + (t & 1) * 16 + c15;
        w0r[t] = Wk[0 * G_ + col];
        w1r[t] = Wk[1 * G_ + col];
        br[t]  = bias[col];
#pragma unroll
        for (int s2 = 0; s2 < 4; ++s2) {
            half8 f;
#pragma unroll
            for (int e = 0; e < 8; ++e) {
                const int k = s2 * 32 + grp * 8 + e;   // 0..127
                f[e] = (_Float16)Wk[(size_t)(2 + k) * G_ + col];
            }
            wf[t][s2] = f;
        }
    }

    if (tid < F_) {
        h_lds[0][tid] = (_Float16)0.f;
        h_lds[1][tid] = (_Float16)0.f;
    }
    __syncthreads();

    float cs0 = 0.f, cs1 = 0.f;        // cell state (lanes 0..15, 2 dims each)
    float4_ acc[8];
#pragma unroll
    for (int t = 0; t < 8; ++t) { acc[t][0] = 0.f; acc[t][1] = 0.f; acc[t][2] = 0.f; acc[t][3] = 0.f; }

    const float* xp = inp + (size_t)bb * N_ * FIN_;
    float* outp = out + (size_t)bb * N_ * F_ + w * 32 + c15;

    // step s uses x_shift[s] = (s==0 ? 0 : inp[s-1])
    float x0 = 0.f, x1 = 0.f;
    for (int s = 0; s < N_; s += 2) {
        // prefetch x for step s+1 (= inp[s])
        const float nx0 = xp[2 * s],     nx1 = xp[2 * s + 1];
        lstm_step(h_lds[s & 2 ? 0 : 0], h_lds[1], wf, w0r, w1r, br, acc,
                  x0, x1, cs0, cs1, outp, lane, c15, grp, w);
        outp += F_;
        // prefetch x for step s+2 (= inp[s+1]); at s=510 reads inp[511] (valid, unused)
        const float mx0 = xp[2 * s + 2], mx1 = xp[2 * s + 3];
        lstm_step(h_lds[1], h_lds[0], wf, w0r, w1r, br, acc,
                  nx0, nx1, cs0, cs1, outp, lane, c15, grp, w);
        outp += F_;
        x0 = mx0; x1 = mx1;
    }
}

extern "C" void kernel_launch(void* const* d_in, const int* in_sizes, int n_in,
                              void* d_out, int out_size, void* d_ws, size_t ws_size,
                              hipStream_t stream) {
    const float* inp  = (const float*)d_in[0];
    const float* Wk   = (const float*)d_in[1];
    const float* bias = (const float*)d_in[2];
    float* out        = (float*)d_out;
    lstm_scan<<<dim3(B_), dim3(256), 0, stream>>>(inp, Wk, bias, out);
}

// Round 3
// 328.131 us; speedup vs baseline: 1.4956x; 1.2248x over previous
//
#include <hip/hip_runtime.h>

#define B_   512
#define N_   512
#define FIN_ 2
#define F_   128
#define G_   512   // 4*F gates

typedef _Float16 half8 __attribute__((ext_vector_type(8)));
typedef float    float4_ __attribute__((ext_vector_type(4)));

__device__ __forceinline__ float sigmoid_(float x) {
    return __builtin_amdgcn_rcpf(1.f + __expf(-x));
}
__device__ __forceinline__ float tanh_(float x) {
    // tanh(x) = 1 - 2/(exp(2x)+1); saturates correctly at +-inf
    return 1.f - 2.f * __builtin_amdgcn_rcpf(1.f + __expf(2.f * x));
}

// One LSTM step for TWO batch rows sharing the MFMA's A rows 0,1.
// 8 waves; wave w owns hidden dims [w*16, w*16+16) x all 4 gates:
// tile t = gate t, col = t*128 + w*16 + c15. C layout (m89): col=lane&15,
// row=(lane>>4)*4+reg -> lanes 0..15 regs 0,1 = batch rows 0,1 -> each lane
// gets all 4 gates for its dim for both rows with NO redistribution.
__device__ __forceinline__ void lstm_step2(
    const _Float16 (&hsrc)[2][F_], _Float16 (&hdst)[2][F_],
    const half8 (&wf)[4][4], const float (&w0r)[4], const float (&w1r)[4],
    const float (&br)[4], float4_ (&acc)[4],
    float x0a, float x1a, float x0b, float x1b,
    float& cs0, float& cs1, float* outA, float* outB,
    int lane, int c15, int grp, int w)
{
    // A row = lane&15; rows>=2 are don't-care, so lane reads row (lane&1):
    // (lane&15)==0 -> row 0, ==1 -> row 1. k = grp*8 + e within slice.
    const int arow = lane & 1;
    half8 af[4];
#pragma unroll
    for (int s2 = 0; s2 < 4; ++s2)
        af[s2] = *reinterpret_cast<const half8*>(&hsrc[arow][s2 * 32 + grp * 8]);

    // C-init rows 0,1 = per-row x-projection + bias (fp32 exact).
    // Regs 2,3 stay stale (bounded garbage, never read).
#pragma unroll
    for (int t = 0; t < 4; ++t) {
        acc[t][0] = fmaf(x0a, w0r[t], fmaf(x1a, w1r[t], br[t]));
        acc[t][1] = fmaf(x0b, w0r[t], fmaf(x1b, w1r[t], br[t]));
    }

    // h @ Wh : 4 gate-tiles x 4 K-slices (K=128)
#pragma unroll
    for (int s2 = 0; s2 < 4; ++s2)
#pragma unroll
        for (int t = 0; t < 4; ++t)
            acc[t] = __builtin_amdgcn_mfma_f32_16x16x32_f16(af[s2], wf[t][s2], acc[t], 0, 0, 0);

    if (lane < 16) {
        const float i0 = sigmoid_(acc[0][0]);
        const float f0 = sigmoid_(acc[1][0]);
        const float g0 = tanh_(acc[2][0]);
        const float o0 = sigmoid_(acc[3][0]);
        cs0 = fmaf(f0, cs0, i0 * g0);
        const float h0 = o0 * tanh_(cs0);
        const float i1 = sigmoid_(acc[0][1]);
        const float f1 = sigmoid_(acc[1][1]);
        const float g1 = tanh_(acc[2][1]);
        const float o1 = sigmoid_(acc[3][1]);
        cs1 = fmaf(f1, cs1, i1 * g1);
        const float h1 = o1 * tanh_(cs1);
        outA[0] = h0;                       // fire-and-forget HBM stores
        outB[0] = h1;
        hdst[0][w * 16 + c15] = (_Float16)h0;
        hdst[1][w * 16 + c15] = (_Float16)h1;
    }
    // LDS-visibility-only barrier: never drain vmcnt in the loop.
    asm volatile("s_waitcnt lgkmcnt(0)\n\ts_barrier" ::: "memory");
}

__global__ void __launch_bounds__(512, 2)
lstm_scan(const float* __restrict__ inp, const float* __restrict__ Wk,
          const float* __restrict__ bias, float* __restrict__ out)
{
    const int bb   = blockIdx.x;       // handles batch rows 2bb, 2bb+1
    const int tid  = threadIdx.x;
    const int w    = tid >> 6;         // wave 0..7, dims [w*16, w*16+16)
    const int lane = tid & 63;
    const int c15  = lane & 15;
    const int grp  = lane >> 4;        // k-group (8 consecutive k)

    __shared__ __align__(16) _Float16 h_lds[2][2][F_];  // [pingpong][row][dim]

    // ---- one-time: weight fragments into registers (64 VGPRs) ----
    half8 wf[4][4];
    float w0r[4], w1r[4], br[4];
#pragma unroll
    for (int t = 0; t < 4; ++t) {
        const int col = t * F_ + w * 16 + c15;
        w0r[t] = Wk[0 * G_ + col];
        w1r[t] = Wk[1 * G_ + col];
        br[t]  = bias[col];
#pragma unroll
        for (int s2 = 0; s2 < 4; ++s2) {
            half8 f;
#pragma unroll
            for (int e = 0; e < 8; ++e) {
                const int k = s2 * 32 + grp * 8 + e;   // 0..127
                f[e] = (_Float16)Wk[(size_t)(2 + k) * G_ + col];
            }
            wf[t][s2] = f;
        }
    }

    ((_Float16*)h_lds)[tid] = (_Float16)0.f;   // 512 entries == blockDim
    __syncthreads();

    float cs0 = 0.f, cs1 = 0.f;        // cell state (lanes 0..15)
    float4_ acc[4];
#pragma unroll
    for (int t = 0; t < 4; ++t) { acc[t][0] = 0.f; acc[t][1] = 0.f; acc[t][2] = 0.f; acc[t][3] = 0.f; }

    const float* xpA = inp + (size_t)(2 * bb) * N_ * FIN_;
    const float* xpB = xpA + N_ * FIN_;
    float* outA = out + (size_t)(2 * bb) * N_ * F_ + w * 16 + c15;
    float* outB = outA + (size_t)N_ * F_;

    // step s uses x_shift[s] = (s==0 ? 0 : inp[s-1]); prefetch one step ahead
    float x0a = 0.f, x1a = 0.f, x0b = 0.f, x1b = 0.f;
    for (int s = 0; s < N_; s += 2) {
        const float nx0a = xpA[2 * s],     nx1a = xpA[2 * s + 1];
        const float nx0b = xpB[2 * s],     nx1b = xpB[2 * s + 1];
        lstm_step2(h_lds[0], h_lds[1], wf, w0r, w1r, br, acc,
                   x0a, x1a, x0b, x1b, cs0, cs1, outA, outB, lane, c15, grp, w);
        outA += F_; outB += F_;
        const float mx0a = xpA[2 * s + 2], mx1a = xpA[2 * s + 3];
        const float mx0b = xpB[2 * s + 2], mx1b = xpB[2 * s + 3];
        lstm_step2(h_lds[1], h_lds[0], wf, w0r, w1r, br, acc,
                   nx0a, nx1a, nx0b, nx1b, cs0, cs1, outA, outB, lane, c15, grp, w);
        outA += F_; outB += F_;
        x0a = mx0a; x1a = mx1a; x0b = mx0b; x1b = mx1b;
    }
}

extern "C" void kernel_launch(void* const* d_in, const int* in_sizes, int n_in,
                              void* d_out, int out_size, void* d_ws, size_t ws_size,
                              hipStream_t stream) {
    const float* inp  = (const float*)d_in[0];
    const float* Wk   = (const float*)d_in[1];
    const float* bias = (const float*)d_in[2];
    float* out        = (float*)d_out;
    lstm_scan<<<dim3(B_ / 2), dim3(512), 0, stream>>>(inp, Wk, bias, out);
}

// Round 4
// 232.253 us; speedup vs baseline: 2.1130x; 1.4128x over previous
//
#include <hip/hip_runtime.h>

#define B_   512
#define N_   512
#define FIN_ 2
#define F_   128
#define G_   512           // 4*F gates
#define XSTRIDE 1040       // floats per x row in LDS (+16 float pad = 64B -> disjoint banks)
#define HSTRIDE 160        // halfs per h row (320B stride -> rows on disjoint bank halves)

typedef _Float16 half8  __attribute__((ext_vector_type(8)));
typedef float    float4_ __attribute__((ext_vector_type(4)));
typedef float    float2_ __attribute__((ext_vector_type(2)));

__device__ __forceinline__ float sigmoid_(float x) {
    return __builtin_amdgcn_rcpf(1.f + __expf(-x));
}
__device__ __forceinline__ float tanh_(float x) {
    // tanh(x) = 1 - 2/(exp(2x)+1); saturates correctly at +-inf
    return 1.f - 2.f * __builtin_amdgcn_rcpf(1.f + __expf(2.f * x));
}

// One LSTM step, two batch rows per block mapped to MFMA A-rows 0 and 4.
// C layout (m89): col=lane&15, row=(lane>>4)*4+reg. Row 0 -> lanes 0-15 reg0
// (batch a), row 4 -> lanes 16-31 reg0 (batch b): gate math runs on 32 lanes,
// each lane owning 1 dim x 4 gates x 1 row, with NO cross-lane redistribution.
__device__ __forceinline__ void lstm_step(
    const _Float16* hsrc,            // per-lane: h_lds[buf] + hrow*HSTRIDE
    _Float16* hdst,                  // per-lane write slot (lanes<32)
    float* outp,                     // per-lane HBM slot (lanes<32)
    const half8 (&wf)[4][4], const float (&w0r)[4], const float (&w1r)[4],
    const float (&br)[4], float4_ (&acc)[4], float2_ xv,
    float& cs, int lane, int grp)
{
    // A-fragments: lane (c15,grp) supplies A[c15][k], k = s2*32+grp*8+e.
    // Rows other than 0,4 are don't-care; hrow=(c15>>2)&1 feeds 0->ha, 4->hb.
    half8 af[4];
#pragma unroll
    for (int s2 = 0; s2 < 4; ++s2)
        af[s2] = *reinterpret_cast<const half8*>(hsrc + s2 * 32 + grp * 8);

    // C-init reg0 = per-row x-projection + bias (fp32 exact); regs 1-3 stale.
#pragma unroll
    for (int t = 0; t < 4; ++t)
        acc[t][0] = fmaf(xv[0], w0r[t], fmaf(xv[1], w1r[t], br[t]));

    // h @ Wh : 4 gate-tiles x 4 K-slices (K=128)
#pragma unroll
    for (int s2 = 0; s2 < 4; ++s2)
#pragma unroll
        for (int t = 0; t < 4; ++t)
            acc[t] = __builtin_amdgcn_mfma_f32_16x16x32_f16(af[s2], wf[t][s2], acc[t], 0, 0, 0);

    if (lane < 32) {
        const float gi = sigmoid_(acc[0][0]);
        const float gf = sigmoid_(acc[1][0]);
        const float gg = tanh_(acc[2][0]);
        const float go = sigmoid_(acc[3][0]);
        cs = fmaf(gf, cs, gi * gg);
        const float h = go * tanh_(cs);
        *outp = h;                    // fire-and-forget; NOTHING ever waits vmcnt
        *hdst = (_Float16)h;
    }
    // LDS-visibility-only barrier: never drain vmcnt in the loop.
    asm volatile("s_waitcnt lgkmcnt(0)\n\ts_barrier" ::: "memory");
}

__global__ void __launch_bounds__(512, 2)
lstm_scan(const float* __restrict__ inp, const float* __restrict__ Wk,
          const float* __restrict__ bias, float* __restrict__ out)
{
    const int bb   = blockIdx.x;       // batch rows 2bb, 2bb+1
    const int tid  = threadIdx.x;
    const int w    = tid >> 6;         // wave 0..7, dims [w*16, w*16+16)
    const int lane = tid & 63;
    const int c15  = lane & 15;
    const int grp  = lane >> 4;        // k-group (8 consecutive k)

    __shared__ __align__(64) _Float16 h_lds[2][2 * HSTRIDE];  // ping-pong h
    __shared__ __align__(64) float    x_lds[2 * XSTRIDE];     // staged inputs

    // ---- one-time: weight fragments into registers (64 VGPRs) ----
    // tile t = gate t, col = t*128 + w*16 + c15
    half8 wf[4][4];
    float w0r[4], w1r[4], br[4];
#pragma unroll
    for (int t = 0; t < 4; ++t) {
        const int col = t * F_ + w * 16 + c15;
        w0r[t] = Wk[col];
        w1r[t] = Wk[G_ + col];
        br[t]  = bias[col];
#pragma unroll
        for (int s2 = 0; s2 < 4; ++s2) {
            half8 f;
#pragma unroll
            for (int e = 0; e < 8; ++e)
                f[e] = (_Float16)Wk[(size_t)(2 + s2 * 32 + grp * 8 + e) * G_ + col];
            wf[t][s2] = f;
        }
    }

    // ---- stage x (2 rows x 1024 floats) into padded LDS ----
    {
        const float* xsrc = inp + (size_t)(2 * bb) * (N_ * FIN_);
        const int i4 = tid * 4;                      // 0..2044
        float4_ v = *reinterpret_cast<const float4_*>(xsrc + i4);
        const int row = i4 >> 10, idx = i4 & 1023;
        *reinterpret_cast<float4_*>(&x_lds[row * XSTRIDE + idx]) = v;
    }
    for (int i = tid; i < 2 * 2 * HSTRIDE; i += 512)
        ((_Float16*)h_lds)[i] = (_Float16)0.f;
    __syncthreads();

    const int r    = (lane >> 4) & 1;   // batch sub-row this lane handles
    const int hrow = (c15 >> 2) & 1;    // h-row feeding this lane's A slot

    const _Float16* hr0 = &h_lds[0][hrow * HSTRIDE];
    const _Float16* hr1 = &h_lds[1][hrow * HSTRIDE];
    _Float16* hw0 = &h_lds[0][r * HSTRIDE + w * 16 + c15];
    _Float16* hw1 = &h_lds[1][r * HSTRIDE + w * 16 + c15];
    const float* xq = &x_lds[r * XSTRIDE];   // x for step s lives at xq[2(s-1)]
    float* outp = out + (size_t)(2 * bb + r) * N_ * F_ + w * 16 + c15;

    float cs = 0.f;
    float4_ acc[4];
#pragma unroll
    for (int t = 0; t < 4; ++t) { acc[t][0] = 0.f; acc[t][1] = 0.f; acc[t][2] = 0.f; acc[t][3] = 0.f; }

    float2_ xz; xz[0] = 0.f; xz[1] = 0.f;

    // step 0: x_shift = 0, reads zeroed buf0, writes buf1
    lstm_step(hr0, hw1, outp, wf, w0r, w1r, br, acc, xz, cs, lane, grp);
    outp += F_;

    // steps 1..510 in pairs (odd reads buf1, even reads buf0)
    for (int i = 0; i < 255; ++i) {
        const int s = 2 * i + 1;
        const float2_ xa = *reinterpret_cast<const float2_*>(xq + 2 * (s - 1));
        const float2_ xb = *reinterpret_cast<const float2_*>(xq + 2 * s);
        lstm_step(hr1, hw0, outp, wf, w0r, w1r, br, acc, xa, cs, lane, grp);
        outp += F_;
        lstm_step(hr0, hw1, outp, wf, w0r, w1r, br, acc, xb, cs, lane, grp);
        outp += F_;
    }
    // step 511 (odd): reads buf1
    {
        const float2_ xa = *reinterpret_cast<const float2_*>(xq + 2 * 510);
        lstm_step(hr1, hw0, outp, wf, w0r, w1r, br, acc, xa, cs, lane, grp);
    }
}

extern "C" void kernel_launch(void* const* d_in, const int* in_sizes, int n_in,
                              void* d_out, int out_size, void* d_ws, size_t ws_size,
                              hipStream_t stream) {
    const float* inp  = (const float*)d_in[0];
    const float* Wk   = (const float*)d_in[1];
    const float* bias = (const float*)d_in[2];
    float* out        = (float*)d_out;
    lstm_scan<<<dim3(B_ / 2), dim3(512), 0, stream>>>(inp, Wk, bias, out);
}